// Round 17
// baseline (2308.199 us; speedup 1.0000x reference)
//
#include <hip/hip_runtime.h>
#include <stdint.h>
#include <math.h>

// Bit-exact replication of img + jax.random.poisson(fold_in(key(0),1), 500, (3,4096,4096)).
// Reference: JAX/XLA:CPU x86+FMA (partitionable threefry, proven r3+).
// Round-17 change (single knob): XLA AlgebraicSimplifier rewrites divide-by-constant
// to multiply-by-reciprocal. The ONLY constant-divisor site in the pipeline is
// lgamma's  z / 7.5  ->  z * (1/7.5f) = z * 0.13333334f  (0x3E088889).
// This perturbs log1p's arg by <=1 ulp on ~half the live integer z's -> log_t ulp
// flips -> ~2.3e-4 t-shifts on a FIXED subset independent of log family — matching
// the flip set frozen across all transcendental variants since r3.
// Everything else: strict HloEvaluator-folded constants (broadcast-sinking model),
// CR log_lam; kq = fma(inner,u,500.43f) [const-merged]; t = fma(k,log_lam,-500) - lg;
// lgamma final = fma(factor,log_t,log_sqrt_2pi) + log(sum); 3-way fused Cephes log.

#pragma clang fp contract(off)

#define TOTAL_ELEMS 50331648u
#define N_BLOCKS    2048
#define N_TPB       256
#define TOTAL_THREADS 524288u          // N_BLOCKS * N_TPB
#define ELEMS_PER_THREAD 96            // 524288 * 96 = 50331648
#define CAP 32

__device__ __forceinline__ uint32_t rotl32(uint32_t v, uint32_t r) {
  return (v << r) | (v >> (32u - r));
}

// Threefry-2x32, 20 rounds, exactly as jax/_src/prng.py
__device__ __forceinline__ void tf2x32(uint32_t k0, uint32_t k1,
                                       uint32_t c0, uint32_t c1,
                                       uint32_t& o0, uint32_t& o1) {
  uint32_t ks2 = k0 ^ k1 ^ 0x1BD11BDAu;
  uint32_t x0 = c0 + k0;
  uint32_t x1 = c1 + k1;
#define TF_R(r) { x0 += x1; x1 = rotl32(x1, r); x1 ^= x0; }
  TF_R(13u) TF_R(15u) TF_R(26u) TF_R(6u)
  x0 += k1;  x1 += ks2 + 1u;
  TF_R(17u) TF_R(29u) TF_R(16u) TF_R(24u)
  x0 += ks2; x1 += k0 + 2u;
  TF_R(13u) TF_R(15u) TF_R(26u) TF_R(6u)
  x0 += k0;  x1 += k1 + 3u;
  TF_R(17u) TF_R(29u) TF_R(16u) TF_R(24u)
  x0 += k1;  x1 += ks2 + 4u;
  TF_R(13u) TF_R(15u) TF_R(26u) TF_R(6u)
  x0 += ks2; x1 += k0 + 5u;
#undef TF_R
  o0 = x0; o1 = x1;
}

// XLA:CPU GenerateVF32Log (llvm_ir_runtime.cc): Cephes 3-way split, DAG-contracted.
__device__ __forceinline__ float xla_logf(float xin) {
  #pragma clang fp contract(off)
  if (xin == 0.0f) return -__builtin_inff();
  if (!(xin > 0.0f)) return __builtin_nanf("");
  float x = fmaxf(xin, __uint_as_float(0x00800000u));   // cut off denormals
  uint32_t ix = __float_as_uint(x);
  float e = 1.0f + (float)((int32_t)(ix >> 23) - 127);
  x = __uint_as_float((ix & 0x807fffffu) | 0x3f000000u);  // mantissa -> [0.5,1)
  const float SQRTHF = (float)0.707106781186547524;
  bool m = x < SQRTHF;
  float tmp1 = m ? x : 0.0f;
  x = x - 1.0f;
  e = e - (m ? 1.0f : 0.0f);
  x = x + tmp1;
  float x2 = x * x;
  float x3 = x2 * x;
  float y  = __builtin_fmaf(x, (float)7.0376836292e-2,  (float)-1.1514610310e-1);
  float y1 = __builtin_fmaf(x, (float)-1.2420140846e-1, (float)1.4249322787e-1);
  float y2 = __builtin_fmaf(x, (float)2.0000714765e-1,  (float)-2.4999993993e-1);
  y  = __builtin_fmaf(y,  x, (float)1.1676998740e-1);
  y1 = __builtin_fmaf(y1, x, (float)-1.6668057665e-1);
  y2 = __builtin_fmaf(y2, x, (float)3.3333331174e-1);
  y  = __builtin_fmaf(y, x3, y1);
  y  = __builtin_fmaf(y, x3, y2);
  float yq1 = (float)-2.12194440e-4 * e;
  y = __builtin_fmaf(y, x3, yq1);        // Add(Mul(y,x3), q1*e) -> fma on op0
  x = __builtin_fmaf(-0.5f, x2, x);      // Sub(x, 0.5*x2) -> fnmadd on x
  x = x + y;
  x = __builtin_fmaf((float)0.693359375, e, x);
  return x;
}

// XLA EmitLog1p (f32): select(|x|<1e-4, fma(-0.5,x,1)*x, log(x+1)); large path here.
__device__ __forceinline__ float xla_log1pf(float x) {
  #pragma clang fp contract(off)
  float for_small = __builtin_fmaf(-0.5f, x, 1.0f) * x;
  float for_large = xla_logf(x + 1.0f);
  return (fabsf(x) < (float)1e-4) ? for_small : for_large;
}

// CHLO/XLA Lgamma, Lanczos g=7 n=9, f32.
// Round-17: z/7.5 -> z * (1/7.5f)  [AlgebraicSimplifier div-by-const -> mul-by-recip]
// log_y = fma(factor, log_t, log_sqrt_two_pi) + log(sum)
__device__ __forceinline__ float xla_lgammaf(float a) {
  #pragma clang fp contract(off)
  float z = a - 1.0f;
  float sum = (float)0.99999999999980993227684700473478;
  sum = sum + (float)676.520368121885098567009190444019   / (z + 1.0f);
  sum = sum + (float)-1259.13921672240287047156078755283  / (z + 2.0f);
  sum = sum + (float)771.3234287776530788486528258894     / (z + 3.0f);
  sum = sum + (float)-176.61502916214059906584551354      / (z + 4.0f);
  sum = sum + (float)12.507343278686904814458936853       / (z + 5.0f);
  sum = sum + (float)-0.13857109526572011689554707        / (z + 6.0f);
  sum = sum + (float)9.984369578019570859563e-6           / (z + 7.0f);
  sum = sum + (float)1.50563273514931155834e-7            / (z + 8.0f);
  float t = (float)7.5 + z;
  float w = z * (float)(1.0 / 7.5);                 // <- THE CHANGE (was z / 7.5f)
  float log_t = (float)2.0149030205422647 + xla_log1pf(w);
  float factor = (z + 0.5f) - t / log_t;
  float log_y = __builtin_fmaf(factor, log_t, (float)0.91893853320467274178)
                + xla_logf(sum);
  return log_y;
}

struct PC { float bb, aa, twoa, inv_alpha, v_r, log_lam; };

__device__ __forceinline__ PC make_pc() {
  #pragma clang fp contract(off)
  PC c;
  // Broadcast-sinking model: constants folded by HloEvaluator, STRICT f32, CR sqrt/log.
  float sq = (float)22.360679774997896;            // f32(sqrt(500)), CR
  c.bb = (float)0.931 + (float)2.53 * sq;          // strict mul then add
  c.aa = (float)-0.059 + (float)0.02483 * c.bb;    // strict mul then add
  c.twoa = 2.0f * c.aa;
  c.inv_alpha = (float)1.1239 + (float)1.1328 / (c.bb - (float)3.4);
  c.v_r = (float)0.9277 - (float)3.6224 / (c.bb - 2.0f);
  c.log_lam = (float)6.2146080984221914;           // CR f32(ln 500)
  return c;
}

__device__ __forceinline__ float bits_to_u01(uint32_t bits) {
  return __uint_as_float((bits >> 9) | 0x3f800000u) - 1.0f;
}

// One Hormann trial; decision-equivalent to accept1 | (~reject & accept2).
__device__ __forceinline__ bool hormann_accept(uint32_t ubits, uint32_t vbits,
                                               const PC& c, float& kout) {
  #pragma clang fp contract(off)
  float u01 = bits_to_u01(ubits);
  float v   = bits_to_u01(vbits);
  float u = u01 - 0.5f;
  float us = 0.5f - fabsf(u);
  float inner = c.twoa / us + c.bb;                   // div+add: no fuse
  float kq = __builtin_fmaf(inner, u, 500.43f);       // const-merged lam+0.43
  float k = floorf(kq);
  kout = k;
  bool accept1 = (us >= (float)0.07) & (v <= c.v_r);
  if (accept1) return true;
  bool reject = (k < 0.0f) | ((us < (float)0.013) & (v > us));
  if (reject) return false;
  float s = xla_logf((v * c.inv_alpha) / (c.aa / (us * us) + c.bb));
  float t = __builtin_fmaf(k, c.log_lam, -500.0f) - xla_lgammaf(k + 1.0f);
  return s <= t;
}

// Partitionable (foldlike) split chain: iteration t:
//   key' = tf(key,(0,0)); subkey_0 = tf(key,(0,1)); subkey_1 = tf(key,(0,2))
__device__ __forceinline__ void build_chain(uint32_t n, uint32_t (&ssub)[CAP][4]) {
  if (threadIdx.x == 0) {
    uint32_t k0, k1;
    tf2x32(0u, 0u, 0u, 1u, k0, k1);   // noise_key = fold_in(key(0), 1)
    for (uint32_t t = 0; t < n; ++t) {
      uint32_t nk0, nk1, s00, s01, s10, s11;
      tf2x32(k0, k1, 0u, 0u, nk0, nk1);   // row0: new key
      tf2x32(k0, k1, 0u, 1u, s00, s01);   // row1: subkey_0 (u draws)
      tf2x32(k0, k1, 0u, 2u, s10, s11);   // row2: subkey_1 (v draws)
      ssub[t][0] = s00; ssub[t][1] = s01;
      ssub[t][2] = s10; ssub[t][3] = s11;
      k0 = nk0; k1 = nk1;
    }
  }
  __syncthreads();
}

// Partitionable random_bits for element e: x0 ^ x1 of tf(subkey, (0, e))
__device__ __forceinline__ uint32_t pbits(uint32_t s0, uint32_t s1, uint32_t e) {
  uint32_t a, b;
  tf2x32(s0, s1, 0u, e, a, b);
  return a ^ b;
}

__global__ void pn_init(uint32_t* nmax) { *nmax = 0u; }

// Pass 1: N = max over elements of (first-accept iteration, 1-based) == while_loop trips
__global__ __launch_bounds__(N_TPB) void pn_pass1(uint32_t* nmax) {
  __shared__ uint32_t ssub[CAP][4];
  __shared__ uint32_t red[N_TPB];
  build_chain(CAP, ssub);
  PC c = make_pc();
  uint32_t tid = blockIdx.x * N_TPB + threadIdx.x;
  uint32_t local_n = 0;
  for (int j = 0; j < ELEMS_PER_THREAD; ++j) {
    uint32_t e = tid + (uint32_t)j * TOTAL_THREADS;
    uint32_t n = CAP;
    for (uint32_t t = 0; t < CAP; ++t) {
      float kk;
      uint32_t ub = pbits(ssub[t][0], ssub[t][1], e);
      uint32_t vb = pbits(ssub[t][2], ssub[t][3], e);
      if (hormann_accept(ub, vb, c, kk)) { n = t + 1u; break; }
    }
    if (n > local_n) local_n = n;
  }
  red[threadIdx.x] = local_n;
  __syncthreads();
  for (int s = N_TPB / 2; s > 0; s >>= 1) {
    if (threadIdx.x < (uint32_t)s) {
      uint32_t o = red[threadIdx.x + s];
      if (o > red[threadIdx.x]) red[threadIdx.x] = o;
    }
    __syncthreads();
  }
  if (threadIdx.x == 0) atomicMax(nmax, red[0]);
}

// Pass 2: last-accept (unguarded select) == first accept scanning t = N-1 .. 0.
__global__ __launch_bounds__(N_TPB) void pn_pass2(const float* __restrict__ img,
                                                  float* __restrict__ out,
                                                  const uint32_t* __restrict__ nptr) {
  __shared__ uint32_t ssub[CAP][4];
  uint32_t N = *nptr;
  if (N < 1u) N = 1u;
  if (N > CAP) N = CAP;
  build_chain(N, ssub);
  PC c = make_pc();
  uint32_t tid = blockIdx.x * N_TPB + threadIdx.x;
  for (int j = 0; j < ELEMS_PER_THREAD; ++j) {
    uint32_t e = tid + (uint32_t)j * TOTAL_THREADS;
    float k_out = -1.0f;   // JAX k_init = -1
    for (int t = (int)N - 1; t >= 0; --t) {
      float kk;
      uint32_t ub = pbits(ssub[t][0], ssub[t][1], e);
      uint32_t vb = pbits(ssub[t][2], ssub[t][3], e);
      if (hormann_accept(ub, vb, c, kk)) { k_out = kk; break; }
    }
    out[e] = img[e] + k_out;
  }
}

extern "C" void kernel_launch(void* const* d_in, const int* in_sizes, int n_in,
                              void* d_out, int out_size, void* d_ws, size_t ws_size,
                              hipStream_t stream) {
  (void)in_sizes; (void)n_in; (void)out_size; (void)ws_size;
  const float* img = (const float*)d_in[0];
  float* out = (float*)d_out;
  uint32_t* nmax = (uint32_t*)d_ws;
  pn_init<<<1, 1, 0, stream>>>(nmax);
  pn_pass1<<<N_BLOCKS, N_TPB, 0, stream>>>(nmax);
  pn_pass2<<<N_BLOCKS, N_TPB, 0, stream>>>(img, out, nmax);
}

// Round 18
// 1497.507 us; speedup vs baseline: 1.5414x; 1.5414x over previous
//
#include <hip/hip_runtime.h>
#include <stdint.h>
#include <math.h>

// Bit-exact replication of img + jax.random.poisson(fold_in(key(0),1), 500, (3,4096,4096)).
// NUMERICS FROZEN (r17, absmax=0.0): partitionable threefry; strict HloEvaluator
// constants; CR log_lam; kq = fma(inner,u,500.43f); t = fma(k,log_lam,-500) - lgamma;
// lgamma final = fma(factor,log_t,c) + log(sum) with z*(1/7.5) recip-mul; 3-way fused
// Cephes log. DO NOT ALTER ANY FP OP.
// Perf r18: t(k) is integer-k-only -> 512-entry LDS table for k in [256,768)
// (bit-identical build), removing the lgamma chain (8 divides + 2 logs) from the
// hot wave-path; off-table k falls back to the identical full computation.

#pragma clang fp contract(off)

#define TOTAL_ELEMS 50331648u
#define N_BLOCKS    2048
#define N_TPB       256
#define TOTAL_THREADS 524288u          // N_BLOCKS * N_TPB
#define ELEMS_PER_THREAD 96            // 524288 * 96 = 50331648
#define CAP 32
#define TAB_LO 256
#define TAB_N  512
#define LOG_LAM ((float)6.2146080984221914)   // CR f32(ln 500)

__device__ __forceinline__ uint32_t rotl32(uint32_t v, uint32_t r) {
  return (v << r) | (v >> (32u - r));
}

// Threefry-2x32, 20 rounds, exactly as jax/_src/prng.py
__device__ __forceinline__ void tf2x32(uint32_t k0, uint32_t k1,
                                       uint32_t c0, uint32_t c1,
                                       uint32_t& o0, uint32_t& o1) {
  uint32_t ks2 = k0 ^ k1 ^ 0x1BD11BDAu;
  uint32_t x0 = c0 + k0;
  uint32_t x1 = c1 + k1;
#define TF_R(r) { x0 += x1; x1 = rotl32(x1, r); x1 ^= x0; }
  TF_R(13u) TF_R(15u) TF_R(26u) TF_R(6u)
  x0 += k1;  x1 += ks2 + 1u;
  TF_R(17u) TF_R(29u) TF_R(16u) TF_R(24u)
  x0 += ks2; x1 += k0 + 2u;
  TF_R(13u) TF_R(15u) TF_R(26u) TF_R(6u)
  x0 += k0;  x1 += k1 + 3u;
  TF_R(17u) TF_R(29u) TF_R(16u) TF_R(24u)
  x0 += k1;  x1 += ks2 + 4u;
  TF_R(13u) TF_R(15u) TF_R(26u) TF_R(6u)
  x0 += ks2; x1 += k0 + 5u;
#undef TF_R
  o0 = x0; o1 = x1;
}

// XLA:CPU GenerateVF32Log: Cephes 3-way split, DAG-contracted. (FROZEN)
__device__ __forceinline__ float xla_logf(float xin) {
  #pragma clang fp contract(off)
  if (xin == 0.0f) return -__builtin_inff();
  if (!(xin > 0.0f)) return __builtin_nanf("");
  float x = fmaxf(xin, __uint_as_float(0x00800000u));
  uint32_t ix = __float_as_uint(x);
  float e = 1.0f + (float)((int32_t)(ix >> 23) - 127);
  x = __uint_as_float((ix & 0x807fffffu) | 0x3f000000u);
  const float SQRTHF = (float)0.707106781186547524;
  bool m = x < SQRTHF;
  float tmp1 = m ? x : 0.0f;
  x = x - 1.0f;
  e = e - (m ? 1.0f : 0.0f);
  x = x + tmp1;
  float x2 = x * x;
  float x3 = x2 * x;
  float y  = __builtin_fmaf(x, (float)7.0376836292e-2,  (float)-1.1514610310e-1);
  float y1 = __builtin_fmaf(x, (float)-1.2420140846e-1, (float)1.4249322787e-1);
  float y2 = __builtin_fmaf(x, (float)2.0000714765e-1,  (float)-2.4999993993e-1);
  y  = __builtin_fmaf(y,  x, (float)1.1676998740e-1);
  y1 = __builtin_fmaf(y1, x, (float)-1.6668057665e-1);
  y2 = __builtin_fmaf(y2, x, (float)3.3333331174e-1);
  y  = __builtin_fmaf(y, x3, y1);
  y  = __builtin_fmaf(y, x3, y2);
  float yq1 = (float)-2.12194440e-4 * e;
  y = __builtin_fmaf(y, x3, yq1);
  x = __builtin_fmaf(-0.5f, x2, x);
  x = x + y;
  x = __builtin_fmaf((float)0.693359375, e, x);
  return x;
}

// XLA EmitLog1p (f32). (FROZEN)
__device__ __forceinline__ float xla_log1pf(float x) {
  #pragma clang fp contract(off)
  float for_small = __builtin_fmaf(-0.5f, x, 1.0f) * x;
  float for_large = xla_logf(x + 1.0f);
  return (fabsf(x) < (float)1e-4) ? for_small : for_large;
}

// CHLO/XLA Lgamma with z*(1/7.5) recip-mul. (FROZEN)
__device__ __forceinline__ float xla_lgammaf(float a) {
  #pragma clang fp contract(off)
  float z = a - 1.0f;
  float sum = (float)0.99999999999980993227684700473478;
  sum = sum + (float)676.520368121885098567009190444019   / (z + 1.0f);
  sum = sum + (float)-1259.13921672240287047156078755283  / (z + 2.0f);
  sum = sum + (float)771.3234287776530788486528258894     / (z + 3.0f);
  sum = sum + (float)-176.61502916214059906584551354      / (z + 4.0f);
  sum = sum + (float)12.507343278686904814458936853       / (z + 5.0f);
  sum = sum + (float)-0.13857109526572011689554707        / (z + 6.0f);
  sum = sum + (float)9.984369578019570859563e-6           / (z + 7.0f);
  sum = sum + (float)1.50563273514931155834e-7            / (z + 8.0f);
  float t = (float)7.5 + z;
  float w = z * (float)(1.0 / 7.5);
  float log_t = (float)2.0149030205422647 + xla_log1pf(w);
  float factor = (z + 0.5f) - t / log_t;
  float log_y = __builtin_fmaf(factor, log_t, (float)0.91893853320467274178)
                + xla_logf(sum);
  return log_y;
}

__device__ __forceinline__ float t_of_k(float k) {
  #pragma clang fp contract(off)
  return __builtin_fmaf(k, LOG_LAM, -500.0f) - xla_lgammaf(k + 1.0f);
}

struct PC { float bb, aa, twoa, inv_alpha, v_r; };

__device__ __forceinline__ PC make_pc() {
  #pragma clang fp contract(off)
  PC c;
  float sq = (float)22.360679774997896;            // f32(sqrt(500)), CR
  c.bb = (float)0.931 + (float)2.53 * sq;
  c.aa = (float)-0.059 + (float)0.02483 * c.bb;
  c.twoa = 2.0f * c.aa;
  c.inv_alpha = (float)1.1239 + (float)1.1328 / (c.bb - (float)3.4);
  c.v_r = (float)0.9277 - (float)3.6224 / (c.bb - 2.0f);
  return c;
}

__device__ __forceinline__ float bits_to_u01(uint32_t bits) {
  return __uint_as_float((bits >> 9) | 0x3f800000u) - 1.0f;
}

// One Hormann trial with LDS t(k)-table fast path. Decision-identical to r17.
__device__ __forceinline__ bool hormann_accept(uint32_t ubits, uint32_t vbits,
                                               const PC& c, const float* __restrict__ ttab,
                                               float& kout) {
  #pragma clang fp contract(off)
  float u01 = bits_to_u01(ubits);
  float v   = bits_to_u01(vbits);
  float u = u01 - 0.5f;
  float us = 0.5f - fabsf(u);
  float inner = c.twoa / us + c.bb;
  float kq = __builtin_fmaf(inner, u, 500.43f);
  float k = floorf(kq);
  kout = k;
  bool accept1 = (us >= (float)0.07) & (v <= c.v_r);
  if (accept1) return true;
  bool reject = (k < 0.0f) | ((us < (float)0.013) & (v > us));
  if (reject) return false;
  float s = xla_logf((v * c.inv_alpha) / (c.aa / (us * us) + c.bb));
  int ki = (int)k;
  float t;
  if (ki >= TAB_LO && ki < TAB_LO + TAB_N) {
    t = ttab[ki - TAB_LO];            // bit-identical precomputed t(k)
  } else {
    t = t_of_k(k);                    // rare off-table fallback (identical ops)
  }
  return s <= t;
}

// Build subkey chain (thread 0) and t(k)-table (all threads); caller must sync after.
__device__ __forceinline__ void build_shared(uint32_t n, uint32_t (&ssub)[CAP][4],
                                             float* ttab) {
  for (uint32_t i = threadIdx.x; i < TAB_N; i += N_TPB) {
    ttab[i] = t_of_k((float)(int)(TAB_LO + (int)i));
  }
  if (threadIdx.x == 0) {
    uint32_t k0, k1;
    tf2x32(0u, 0u, 0u, 1u, k0, k1);   // noise_key = fold_in(key(0), 1)
    for (uint32_t t = 0; t < n; ++t) {
      uint32_t nk0, nk1, s00, s01, s10, s11;
      tf2x32(k0, k1, 0u, 0u, nk0, nk1);
      tf2x32(k0, k1, 0u, 1u, s00, s01);
      tf2x32(k0, k1, 0u, 2u, s10, s11);
      ssub[t][0] = s00; ssub[t][1] = s01;
      ssub[t][2] = s10; ssub[t][3] = s11;
      k0 = nk0; k1 = nk1;
    }
  }
  __syncthreads();
}

// Partitionable random_bits for element e: x0 ^ x1 of tf(subkey, (0, e))
__device__ __forceinline__ uint32_t pbits(uint32_t s0, uint32_t s1, uint32_t e) {
  uint32_t a, b;
  tf2x32(s0, s1, 0u, e, a, b);
  return a ^ b;
}

__global__ void pn_init(uint32_t* nmax) { *nmax = 0u; }

// Pass 1: N = max over elements of (first-accept iteration, 1-based)
__global__ __launch_bounds__(N_TPB) void pn_pass1(uint32_t* nmax) {
  __shared__ uint32_t ssub[CAP][4];
  __shared__ float ttab[TAB_N];
  __shared__ uint32_t red[N_TPB];
  build_shared(CAP, ssub, ttab);
  PC c = make_pc();
  uint32_t tid = blockIdx.x * N_TPB + threadIdx.x;
  uint32_t local_n = 0;
  for (int j = 0; j < ELEMS_PER_THREAD; ++j) {
    uint32_t e = tid + (uint32_t)j * TOTAL_THREADS;
    uint32_t n = CAP;
    #pragma unroll 1
    for (uint32_t t = 0; t < CAP; ++t) {
      float kk;
      uint32_t ub = pbits(ssub[t][0], ssub[t][1], e);
      uint32_t vb = pbits(ssub[t][2], ssub[t][3], e);
      if (hormann_accept(ub, vb, c, ttab, kk)) { n = t + 1u; break; }
    }
    if (n > local_n) local_n = n;
  }
  red[threadIdx.x] = local_n;
  __syncthreads();
  for (int s = N_TPB / 2; s > 0; s >>= 1) {
    if (threadIdx.x < (uint32_t)s) {
      uint32_t o = red[threadIdx.x + s];
      if (o > red[threadIdx.x]) red[threadIdx.x] = o;
    }
    __syncthreads();
  }
  if (threadIdx.x == 0) atomicMax(nmax, red[0]);
}

// Pass 2: last-accept == first accept scanning t = N-1 .. 0.
__global__ __launch_bounds__(N_TPB) void pn_pass2(const float* __restrict__ img,
                                                  float* __restrict__ out,
                                                  const uint32_t* __restrict__ nptr) {
  __shared__ uint32_t ssub[CAP][4];
  __shared__ float ttab[TAB_N];
  uint32_t N = *nptr;
  if (N < 1u) N = 1u;
  if (N > CAP) N = CAP;
  build_shared(N, ssub, ttab);
  PC c = make_pc();
  uint32_t tid = blockIdx.x * N_TPB + threadIdx.x;
  for (int j = 0; j < ELEMS_PER_THREAD; ++j) {
    uint32_t e = tid + (uint32_t)j * TOTAL_THREADS;
    float k_out = -1.0f;   // JAX k_init = -1
    #pragma unroll 1
    for (int t = (int)N - 1; t >= 0; --t) {
      float kk;
      uint32_t ub = pbits(ssub[t][0], ssub[t][1], e);
      uint32_t vb = pbits(ssub[t][2], ssub[t][3], e);
      if (hormann_accept(ub, vb, c, ttab, kk)) { k_out = kk; break; }
    }
    out[e] = img[e] + k_out;
  }
}

extern "C" void kernel_launch(void* const* d_in, const int* in_sizes, int n_in,
                              void* d_out, int out_size, void* d_ws, size_t ws_size,
                              hipStream_t stream) {
  (void)in_sizes; (void)n_in; (void)out_size; (void)ws_size;
  const float* img = (const float*)d_in[0];
  float* out = (float*)d_out;
  uint32_t* nmax = (uint32_t*)d_ws;
  pn_init<<<1, 1, 0, stream>>>(nmax);
  pn_pass1<<<N_BLOCKS, N_TPB, 0, stream>>>(nmax);
  pn_pass2<<<N_BLOCKS, N_TPB, 0, stream>>>(img, out, nmax);
}

// Round 19
// 821.201 us; speedup vs baseline: 2.8108x; 1.8236x over previous
//
#include <hip/hip_runtime.h>
#include <stdint.h>
#include <math.h>

// Bit-exact replication of img + jax.random.poisson(fold_in(key(0),1), 500, (3,4096,4096)).
// NUMERICS FROZEN (r17, absmax=0.0): partitionable threefry; strict HloEvaluator
// constants; CR log_lam; kq = fma(inner,u,500.43f); t = fma(k,log_lam,-500) - lgamma;
// lgamma final = fma(factor,log_t,c) + log(sum) with z*(1/7.5) recip-mul; 3-way fused
// Cephes log; t(k) LDS table (r18). DO NOT ALTER ANY FP OP.
// Perf r19: level-synchronous queue compaction — process trial-levels breadth-first,
// compacting failures into an LDS queue, converting 2.9 divergent wave-iters/element
// into ~1.2 coherent trials/element. Decisions bit-identical; order-only change.

#pragma clang fp contract(off)

#define TOTAL_ELEMS 50331648u
#define N_BLOCKS    2048
#define N_TPB       256
#define TOTAL_THREADS 524288u          // N_BLOCKS * N_TPB
#define ELEMS_PER_THREAD 96            // 524288 * 96 = 50331648
#define CAP 32
#define TAB_LO 256
#define TAB_N  512
#define QCAP 3072                      // mean failures 2826 + 4.9 sigma; fallback covers rest
#define LOG_LAM ((float)6.2146080984221914)   // CR f32(ln 500)

__device__ __forceinline__ uint32_t rotl32(uint32_t v, uint32_t r) {
  return (v << r) | (v >> (32u - r));
}

// Threefry-2x32, 20 rounds, exactly as jax/_src/prng.py
__device__ __forceinline__ void tf2x32(uint32_t k0, uint32_t k1,
                                       uint32_t c0, uint32_t c1,
                                       uint32_t& o0, uint32_t& o1) {
  uint32_t ks2 = k0 ^ k1 ^ 0x1BD11BDAu;
  uint32_t x0 = c0 + k0;
  uint32_t x1 = c1 + k1;
#define TF_R(r) { x0 += x1; x1 = rotl32(x1, r); x1 ^= x0; }
  TF_R(13u) TF_R(15u) TF_R(26u) TF_R(6u)
  x0 += k1;  x1 += ks2 + 1u;
  TF_R(17u) TF_R(29u) TF_R(16u) TF_R(24u)
  x0 += ks2; x1 += k0 + 2u;
  TF_R(13u) TF_R(15u) TF_R(26u) TF_R(6u)
  x0 += k0;  x1 += k1 + 3u;
  TF_R(17u) TF_R(29u) TF_R(16u) TF_R(24u)
  x0 += k1;  x1 += ks2 + 4u;
  TF_R(13u) TF_R(15u) TF_R(26u) TF_R(6u)
  x0 += ks2; x1 += k0 + 5u;
#undef TF_R
  o0 = x0; o1 = x1;
}

// XLA:CPU GenerateVF32Log: Cephes 3-way split, DAG-contracted. (FROZEN)
__device__ __forceinline__ float xla_logf(float xin) {
  #pragma clang fp contract(off)
  if (xin == 0.0f) return -__builtin_inff();
  if (!(xin > 0.0f)) return __builtin_nanf("");
  float x = fmaxf(xin, __uint_as_float(0x00800000u));
  uint32_t ix = __float_as_uint(x);
  float e = 1.0f + (float)((int32_t)(ix >> 23) - 127);
  x = __uint_as_float((ix & 0x807fffffu) | 0x3f000000u);
  const float SQRTHF = (float)0.707106781186547524;
  bool m = x < SQRTHF;
  float tmp1 = m ? x : 0.0f;
  x = x - 1.0f;
  e = e - (m ? 1.0f : 0.0f);
  x = x + tmp1;
  float x2 = x * x;
  float x3 = x2 * x;
  float y  = __builtin_fmaf(x, (float)7.0376836292e-2,  (float)-1.1514610310e-1);
  float y1 = __builtin_fmaf(x, (float)-1.2420140846e-1, (float)1.4249322787e-1);
  float y2 = __builtin_fmaf(x, (float)2.0000714765e-1,  (float)-2.4999993993e-1);
  y  = __builtin_fmaf(y,  x, (float)1.1676998740e-1);
  y1 = __builtin_fmaf(y1, x, (float)-1.6668057665e-1);
  y2 = __builtin_fmaf(y2, x, (float)3.3333331174e-1);
  y  = __builtin_fmaf(y, x3, y1);
  y  = __builtin_fmaf(y, x3, y2);
  float yq1 = (float)-2.12194440e-4 * e;
  y = __builtin_fmaf(y, x3, yq1);
  x = __builtin_fmaf(-0.5f, x2, x);
  x = x + y;
  x = __builtin_fmaf((float)0.693359375, e, x);
  return x;
}

// XLA EmitLog1p (f32). (FROZEN)
__device__ __forceinline__ float xla_log1pf(float x) {
  #pragma clang fp contract(off)
  float for_small = __builtin_fmaf(-0.5f, x, 1.0f) * x;
  float for_large = xla_logf(x + 1.0f);
  return (fabsf(x) < (float)1e-4) ? for_small : for_large;
}

// CHLO/XLA Lgamma with z*(1/7.5) recip-mul. (FROZEN)
__device__ __forceinline__ float xla_lgammaf(float a) {
  #pragma clang fp contract(off)
  float z = a - 1.0f;
  float sum = (float)0.99999999999980993227684700473478;
  sum = sum + (float)676.520368121885098567009190444019   / (z + 1.0f);
  sum = sum + (float)-1259.13921672240287047156078755283  / (z + 2.0f);
  sum = sum + (float)771.3234287776530788486528258894     / (z + 3.0f);
  sum = sum + (float)-176.61502916214059906584551354      / (z + 4.0f);
  sum = sum + (float)12.507343278686904814458936853       / (z + 5.0f);
  sum = sum + (float)-0.13857109526572011689554707        / (z + 6.0f);
  sum = sum + (float)9.984369578019570859563e-6           / (z + 7.0f);
  sum = sum + (float)1.50563273514931155834e-7            / (z + 8.0f);
  float t = (float)7.5 + z;
  float w = z * (float)(1.0 / 7.5);
  float log_t = (float)2.0149030205422647 + xla_log1pf(w);
  float factor = (z + 0.5f) - t / log_t;
  float log_y = __builtin_fmaf(factor, log_t, (float)0.91893853320467274178)
                + xla_logf(sum);
  return log_y;
}

__device__ __forceinline__ float t_of_k(float k) {
  #pragma clang fp contract(off)
  return __builtin_fmaf(k, LOG_LAM, -500.0f) - xla_lgammaf(k + 1.0f);
}

struct PC { float bb, aa, twoa, inv_alpha, v_r; };

__device__ __forceinline__ PC make_pc() {
  #pragma clang fp contract(off)
  PC c;
  float sq = (float)22.360679774997896;            // f32(sqrt(500)), CR
  c.bb = (float)0.931 + (float)2.53 * sq;
  c.aa = (float)-0.059 + (float)0.02483 * c.bb;
  c.twoa = 2.0f * c.aa;
  c.inv_alpha = (float)1.1239 + (float)1.1328 / (c.bb - (float)3.4);
  c.v_r = (float)0.9277 - (float)3.6224 / (c.bb - 2.0f);
  return c;
}

__device__ __forceinline__ float bits_to_u01(uint32_t bits) {
  return __uint_as_float((bits >> 9) | 0x3f800000u) - 1.0f;
}

// One Hormann trial with LDS t(k)-table fast path. Decision-identical to r17.
__device__ __forceinline__ bool hormann_accept(uint32_t ubits, uint32_t vbits,
                                               const PC& c, const float* __restrict__ ttab,
                                               float& kout) {
  #pragma clang fp contract(off)
  float u01 = bits_to_u01(ubits);
  float v   = bits_to_u01(vbits);
  float u = u01 - 0.5f;
  float us = 0.5f - fabsf(u);
  float inner = c.twoa / us + c.bb;
  float kq = __builtin_fmaf(inner, u, 500.43f);
  float k = floorf(kq);
  kout = k;
  bool accept1 = (us >= (float)0.07) & (v <= c.v_r);
  if (accept1) return true;
  bool reject = (k < 0.0f) | ((us < (float)0.013) & (v > us));
  if (reject) return false;
  float s = xla_logf((v * c.inv_alpha) / (c.aa / (us * us) + c.bb));
  int ki = (int)k;
  float t;
  if (ki >= TAB_LO && ki < TAB_LO + TAB_N) t = ttab[ki - TAB_LO];
  else t = t_of_k(k);
  return s <= t;
}

// Partitionable random_bits for element e: x0 ^ x1 of tf(subkey, (0, e))
__device__ __forceinline__ uint32_t pbits(uint32_t s0, uint32_t s1, uint32_t e) {
  uint32_t a, b;
  tf2x32(s0, s1, 0u, e, a, b);
  return a ^ b;
}

// One trial of element e at level t. Returns accept, kout.
__device__ __forceinline__ bool trial(uint32_t e, uint32_t tlvl,
                                      const uint32_t (&ssub)[CAP][4],
                                      const PC& c, const float* __restrict__ ttab,
                                      float& kout) {
  uint32_t ub = pbits(ssub[tlvl][0], ssub[tlvl][1], e);
  uint32_t vb = pbits(ssub[tlvl][2], ssub[tlvl][3], e);
  return hormann_accept(ub, vb, c, ttab, kout);
}

// Build subkey chain (thread 0) and t(k)-table (all threads); caller must sync after.
__device__ __forceinline__ void build_shared(uint32_t n, uint32_t (&ssub)[CAP][4],
                                             float* ttab) {
  for (uint32_t i = threadIdx.x; i < TAB_N; i += N_TPB) {
    ttab[i] = t_of_k((float)(int)(TAB_LO + (int)i));
  }
  if (threadIdx.x == 0) {
    uint32_t k0, k1;
    tf2x32(0u, 0u, 0u, 1u, k0, k1);   // noise_key = fold_in(key(0), 1)
    for (uint32_t t = 0; t < n; ++t) {
      uint32_t nk0, nk1, s00, s01, s10, s11;
      tf2x32(k0, k1, 0u, 0u, nk0, nk1);
      tf2x32(k0, k1, 0u, 1u, s00, s01);
      tf2x32(k0, k1, 0u, 2u, s10, s11);
      ssub[t][0] = s00; ssub[t][1] = s01;
      ssub[t][2] = s10; ssub[t][3] = s11;
      k0 = nk0; k1 = nk1;
    }
  }
  __syncthreads();
}

__global__ void pn_init(uint32_t* nmax) { *nmax = 0u; }

// Pass 1: N = 1 + max over elements of first-accept level (level-synchronous).
__global__ __launch_bounds__(N_TPB) void pn_pass1(uint32_t* nmax) {
  __shared__ uint32_t ssub[CAP][4];
  __shared__ float ttab[TAB_N];
  __shared__ uint32_t q[2][QCAP];
  __shared__ uint32_t qn[2];
  __shared__ uint32_t shN;
  if (threadIdx.x == 0) { qn[0] = 0; qn[1] = 0; shN = 1; }
  build_shared(CAP, ssub, ttab);
  PC c = make_pc();
  uint32_t tid_g = blockIdx.x * N_TPB + threadIdx.x;
  // Phase A: level 0 for all elements, coherent.
  for (int j = 0; j < ELEMS_PER_THREAD; ++j) {
    uint32_t e = tid_g + (uint32_t)j * TOTAL_THREADS;
    float kk;
    if (!trial(e, 0u, ssub, c, ttab, kk)) {
      uint32_t idx = atomicAdd(&qn[0], 1u);
      if (__builtin_expect(idx < QCAP, 1)) q[0][idx] = e;
      else {  // overflow fallback (statistically never): scan upward inline
        uint32_t Lc = CAP;
        for (uint32_t t2 = 1; t2 < CAP; ++t2) {
          if (trial(e, t2, ssub, c, ttab, kk)) { Lc = t2 + 1u; break; }
        }
        atomicMax(&shN, Lc);
      }
    }
  }
  __syncthreads();
  int cur = 0;
  uint32_t localN = 1;
  for (uint32_t t = 1; t < CAP; ++t) {
    uint32_t n = qn[cur]; if (n > QCAP) n = QCAP;
    if (n == 0) break;
    localN = t + 1u;
    if (threadIdx.x == 0) qn[cur ^ 1] = 0;
    __syncthreads();
    for (uint32_t i = threadIdx.x; i < n; i += N_TPB) {
      uint32_t e = q[cur][i];
      float kk;
      if (!trial(e, t, ssub, c, ttab, kk)) {
        uint32_t idx = atomicAdd(&qn[cur ^ 1], 1u);
        if (__builtin_expect(idx < QCAP, 1)) q[cur ^ 1][idx] = e;
        else {
          uint32_t Lc = CAP;
          for (uint32_t t2 = t + 1; t2 < CAP; ++t2) {
            if (trial(e, t2, ssub, c, ttab, kk)) { Lc = t2 + 1u; break; }
          }
          atomicMax(&shN, Lc);
        }
      }
    }
    __syncthreads();
    cur ^= 1;
  }
  __syncthreads();
  if (threadIdx.x == 0) {
    uint32_t m = shN; if (localN > m) m = localN;
    atomicMax(nmax, m);
  }
}

// Pass 2: last-accept == first accept scanning levels N-1 .. 0, level-synchronous.
__global__ __launch_bounds__(N_TPB) void pn_pass2(const float* __restrict__ img,
                                                  float* __restrict__ out,
                                                  const uint32_t* __restrict__ nptr) {
  __shared__ uint32_t ssub[CAP][4];
  __shared__ float ttab[TAB_N];
  __shared__ uint32_t q[2][QCAP];
  __shared__ uint32_t qn[2];
  uint32_t N = *nptr;
  if (N < 1u) N = 1u;
  if (N > CAP) N = CAP;
  if (threadIdx.x == 0) { qn[0] = 0; qn[1] = 0; }
  build_shared(N, ssub, ttab);
  PC c = make_pc();
  uint32_t tid_g = blockIdx.x * N_TPB + threadIdx.x;
  uint32_t top = N - 1u;
  // Phase A: level N-1 for all elements, coherent; coalesced IO on accept.
  for (int j = 0; j < ELEMS_PER_THREAD; ++j) {
    uint32_t e = tid_g + (uint32_t)j * TOTAL_THREADS;
    float kk;
    if (trial(e, top, ssub, c, ttab, kk)) {
      out[e] = img[e] + kk;
    } else {
      uint32_t idx = atomicAdd(&qn[0], 1u);
      if (__builtin_expect(idx < QCAP, 1)) q[0][idx] = e;
      else {  // overflow fallback: full downward scan inline
        float kf = -1.0f;
        for (int t2 = (int)top - 1; t2 >= 0; --t2) {
          if (trial(e, (uint32_t)t2, ssub, c, ttab, kk)) { kf = kk; break; }
        }
        out[e] = img[e] + kf;
      }
    }
  }
  __syncthreads();
  int cur = 0;
  for (int t = (int)top - 1; t >= 0; --t) {
    uint32_t n = qn[cur]; if (n > QCAP) n = QCAP;
    if (n == 0) break;
    if (threadIdx.x == 0) qn[cur ^ 1] = 0;
    __syncthreads();
    for (uint32_t i = threadIdx.x; i < n; i += N_TPB) {
      uint32_t e = q[cur][i];
      float kk;
      if (trial(e, (uint32_t)t, ssub, c, ttab, kk)) {
        out[e] = img[e] + kk;
      } else {
        uint32_t idx = atomicAdd(&qn[cur ^ 1], 1u);
        if (__builtin_expect(idx < QCAP, 1)) q[cur ^ 1][idx] = e;
        else {
          float kf = -1.0f;
          for (int t2 = t - 1; t2 >= 0; --t2) {
            if (trial(e, (uint32_t)t2, ssub, c, ttab, kk)) { kf = kk; break; }
          }
          out[e] = img[e] + kf;
        }
      }
    }
    __syncthreads();
    cur ^= 1;
  }
  // Drain: elements that rejected at all levels N-1..0 -> k = -1 (JAX k_init).
  uint32_t n = qn[cur]; if (n > QCAP) n = QCAP;
  for (uint32_t i = threadIdx.x; i < n; i += N_TPB) {
    uint32_t e = q[cur][i];
    out[e] = img[e] - 1.0f;
  }
}

extern "C" void kernel_launch(void* const* d_in, const int* in_sizes, int n_in,
                              void* d_out, int out_size, void* d_ws, size_t ws_size,
                              hipStream_t stream) {
  (void)in_sizes; (void)n_in; (void)out_size; (void)ws_size;
  const float* img = (const float*)d_in[0];
  float* out = (float*)d_out;
  uint32_t* nmax = (uint32_t*)d_ws;
  pn_init<<<1, 1, 0, stream>>>(nmax);
  pn_pass1<<<N_BLOCKS, N_TPB, 0, stream>>>(nmax);
  pn_pass2<<<N_BLOCKS, N_TPB, 0, stream>>>(img, out, nmax);
}

// Round 20
// 802.472 us; speedup vs baseline: 2.8764x; 1.0233x over previous
//
#include <hip/hip_runtime.h>
#include <stdint.h>
#include <math.h>

// Bit-exact replication of img + jax.random.poisson(fold_in(key(0),1), 500, (3,4096,4096)).
// NUMERICS FROZEN (r17, absmax=0.0). Perf r20: uint16 queues, accept2 deferral with
// chunked dense flush, wave-aggregated queue pushes. Order-only changes.

#pragma clang fp contract(off)

#define TOTAL_ELEMS 50331648u
#define N_BLOCKS    2048
#define N_TPB       256
#define TOTAL_THREADS 524288u          // N_BLOCKS * N_TPB
#define ELEMS_PER_THREAD 96            // 524288 * 96 = 50331648
#define CAP 32
#define TAB_LO 256
#define TAB_N  512
#define QCAP 3072                      // reject-queue cap (mean 2826 + 4.9 sigma)
#define CHUNK_J 4
#define AQ_CAP 384                     // accept2/pending cap per 1024-elem chunk (mean ~266)
#define LOG_LAM ((float)6.2146080984221914)   // CR f32(ln 500)

__device__ __forceinline__ uint32_t rotl32(uint32_t v, uint32_t r) {
  return (v << r) | (v >> (32u - r));
}

// Threefry-2x32, 20 rounds, exactly as jax/_src/prng.py
__device__ __forceinline__ void tf2x32(uint32_t k0, uint32_t k1,
                                       uint32_t c0, uint32_t c1,
                                       uint32_t& o0, uint32_t& o1) {
  uint32_t ks2 = k0 ^ k1 ^ 0x1BD11BDAu;
  uint32_t x0 = c0 + k0;
  uint32_t x1 = c1 + k1;
#define TF_R(r) { x0 += x1; x1 = rotl32(x1, r); x1 ^= x0; }
  TF_R(13u) TF_R(15u) TF_R(26u) TF_R(6u)
  x0 += k1;  x1 += ks2 + 1u;
  TF_R(17u) TF_R(29u) TF_R(16u) TF_R(24u)
  x0 += ks2; x1 += k0 + 2u;
  TF_R(13u) TF_R(15u) TF_R(26u) TF_R(6u)
  x0 += k0;  x1 += k1 + 3u;
  TF_R(17u) TF_R(29u) TF_R(16u) TF_R(24u)
  x0 += k1;  x1 += ks2 + 4u;
  TF_R(13u) TF_R(15u) TF_R(26u) TF_R(6u)
  x0 += ks2; x1 += k0 + 5u;
#undef TF_R
  o0 = x0; o1 = x1;
}

// XLA:CPU GenerateVF32Log: Cephes 3-way split, DAG-contracted. (FROZEN)
__device__ __forceinline__ float xla_logf(float xin) {
  #pragma clang fp contract(off)
  if (xin == 0.0f) return -__builtin_inff();
  if (!(xin > 0.0f)) return __builtin_nanf("");
  float x = fmaxf(xin, __uint_as_float(0x00800000u));
  uint32_t ix = __float_as_uint(x);
  float e = 1.0f + (float)((int32_t)(ix >> 23) - 127);
  x = __uint_as_float((ix & 0x807fffffu) | 0x3f000000u);
  const float SQRTHF = (float)0.707106781186547524;
  bool m = x < SQRTHF;
  float tmp1 = m ? x : 0.0f;
  x = x - 1.0f;
  e = e - (m ? 1.0f : 0.0f);
  x = x + tmp1;
  float x2 = x * x;
  float x3 = x2 * x;
  float y  = __builtin_fmaf(x, (float)7.0376836292e-2,  (float)-1.1514610310e-1);
  float y1 = __builtin_fmaf(x, (float)-1.2420140846e-1, (float)1.4249322787e-1);
  float y2 = __builtin_fmaf(x, (float)2.0000714765e-1,  (float)-2.4999993993e-1);
  y  = __builtin_fmaf(y,  x, (float)1.1676998740e-1);
  y1 = __builtin_fmaf(y1, x, (float)-1.6668057665e-1);
  y2 = __builtin_fmaf(y2, x, (float)3.3333331174e-1);
  y  = __builtin_fmaf(y, x3, y1);
  y  = __builtin_fmaf(y, x3, y2);
  float yq1 = (float)-2.12194440e-4 * e;
  y = __builtin_fmaf(y, x3, yq1);
  x = __builtin_fmaf(-0.5f, x2, x);
  x = x + y;
  x = __builtin_fmaf((float)0.693359375, e, x);
  return x;
}

// XLA EmitLog1p (f32). (FROZEN)
__device__ __forceinline__ float xla_log1pf(float x) {
  #pragma clang fp contract(off)
  float for_small = __builtin_fmaf(-0.5f, x, 1.0f) * x;
  float for_large = xla_logf(x + 1.0f);
  return (fabsf(x) < (float)1e-4) ? for_small : for_large;
}

// CHLO/XLA Lgamma with z*(1/7.5) recip-mul. (FROZEN)
__device__ __forceinline__ float xla_lgammaf(float a) {
  #pragma clang fp contract(off)
  float z = a - 1.0f;
  float sum = (float)0.99999999999980993227684700473478;
  sum = sum + (float)676.520368121885098567009190444019   / (z + 1.0f);
  sum = sum + (float)-1259.13921672240287047156078755283  / (z + 2.0f);
  sum = sum + (float)771.3234287776530788486528258894     / (z + 3.0f);
  sum = sum + (float)-176.61502916214059906584551354      / (z + 4.0f);
  sum = sum + (float)12.507343278686904814458936853       / (z + 5.0f);
  sum = sum + (float)-0.13857109526572011689554707        / (z + 6.0f);
  sum = sum + (float)9.984369578019570859563e-6           / (z + 7.0f);
  sum = sum + (float)1.50563273514931155834e-7            / (z + 8.0f);
  float t = (float)7.5 + z;
  float w = z * (float)(1.0 / 7.5);
  float log_t = (float)2.0149030205422647 + xla_log1pf(w);
  float factor = (z + 0.5f) - t / log_t;
  float log_y = __builtin_fmaf(factor, log_t, (float)0.91893853320467274178)
                + xla_logf(sum);
  return log_y;
}

__device__ __forceinline__ float t_of_k(float k) {
  #pragma clang fp contract(off)
  return __builtin_fmaf(k, LOG_LAM, -500.0f) - xla_lgammaf(k + 1.0f);
}

struct PC { float bb, aa, twoa, inv_alpha, v_r; };

__device__ __forceinline__ PC make_pc() {
  #pragma clang fp contract(off)
  PC c;
  float sq = (float)22.360679774997896;            // f32(sqrt(500)), CR
  c.bb = (float)0.931 + (float)2.53 * sq;
  c.aa = (float)-0.059 + (float)0.02483 * c.bb;
  c.twoa = 2.0f * c.aa;
  c.inv_alpha = (float)1.1239 + (float)1.1328 / (c.bb - (float)3.4);
  c.v_r = (float)0.9277 - (float)3.6224 / (c.bb - 2.0f);
  return c;
}

__device__ __forceinline__ float bits_to_u01(uint32_t bits) {
  return __uint_as_float((bits >> 9) | 0x3f800000u) - 1.0f;
}

__device__ __forceinline__ float t_lookup(float k, const float* __restrict__ ttab) {
  int ki = (int)k;
  if (ki >= TAB_LO && ki < TAB_LO + TAB_N) return ttab[ki - TAB_LO];
  return t_of_k(k);
}

// Full Hormann trial (queue phases / fallbacks). Decision-identical to r17.
__device__ __forceinline__ bool hormann_accept(uint32_t ubits, uint32_t vbits,
                                               const PC& c, const float* __restrict__ ttab,
                                               float& kout) {
  #pragma clang fp contract(off)
  float u01 = bits_to_u01(ubits);
  float v   = bits_to_u01(vbits);
  float u = u01 - 0.5f;
  float us = 0.5f - fabsf(u);
  float inner = c.twoa / us + c.bb;
  float kq = __builtin_fmaf(inner, u, 500.43f);
  float k = floorf(kq);
  kout = k;
  bool accept1 = (us >= (float)0.07) & (v <= c.v_r);
  if (accept1) return true;
  bool reject = (k < 0.0f) | ((us < (float)0.013) & (v > us));
  if (reject) return false;
  float s = xla_logf((v * c.inv_alpha) / (c.aa / (us * us) + c.bb));
  return s <= t_lookup(k, ttab);
}

__device__ __forceinline__ uint32_t pbits(uint32_t s0, uint32_t s1, uint32_t e) {
  uint32_t a, b;
  tf2x32(s0, s1, 0u, e, a, b);
  return a ^ b;
}

__device__ __forceinline__ bool trial(uint32_t e, uint32_t tlvl,
                                      const uint32_t (&ssub)[CAP][4],
                                      const PC& c, const float* __restrict__ ttab,
                                      float& kout) {
  uint32_t ub = pbits(ssub[tlvl][0], ssub[tlvl][1], e);
  uint32_t vb = pbits(ssub[tlvl][2], ssub[tlvl][3], e);
  return hormann_accept(ub, vb, c, ttab, kout);
}

__device__ __forceinline__ uint32_t lane_id() {
  return __builtin_amdgcn_mbcnt_hi(~0u, __builtin_amdgcn_mbcnt_lo(~0u, 0u));
}

// Wave-aggregated queue push: one atomicAdd per wave. Returns slot (or garbage if !push).
__device__ __forceinline__ uint32_t wq_push(uint32_t* counter, bool push) {
  uint64_t mask = __ballot(push);
  if (mask == 0ull) return 0xFFFFFFFFu;
  uint32_t lane = lane_id();
  int leader = (int)(__ffsll((unsigned long long)mask) - 1);
  uint32_t base = 0;
  if ((int)lane == leader) base = atomicAdd(counter, (uint32_t)__popcll(mask));
  base = (uint32_t)__shfl((int)base, leader);
  uint32_t off = (uint32_t)__popcll(mask & ((1ull << lane) - 1ull));
  return base + off;
}

// Build subkey chain (thread 0) and t(k)-table; caller syncs via this.
__device__ __forceinline__ void build_shared(uint32_t n, uint32_t (&ssub)[CAP][4],
                                             float* ttab) {
  for (uint32_t i = threadIdx.x; i < TAB_N; i += N_TPB) {
    ttab[i] = t_of_k((float)(int)(TAB_LO + (int)i));
  }
  if (threadIdx.x == 0) {
    uint32_t k0, k1;
    tf2x32(0u, 0u, 0u, 1u, k0, k1);   // noise_key = fold_in(key(0), 1)
    for (uint32_t t = 0; t < n; ++t) {
      uint32_t nk0, nk1, s00, s01, s10, s11;
      tf2x32(k0, k1, 0u, 0u, nk0, nk1);
      tf2x32(k0, k1, 0u, 1u, s00, s01);
      tf2x32(k0, k1, 0u, 2u, s10, s11);
      ssub[t][0] = s00; ssub[t][1] = s01;
      ssub[t][2] = s10; ssub[t][3] = s11;
      k0 = nk0; k1 = nk1;
    }
  }
  __syncthreads();
}

__global__ void pn_init(uint32_t* nmax) { *nmax = 0u; }

// ---------------- Pass 1: N = 1 + max first-accept level ----------------
__global__ __launch_bounds__(N_TPB) void pn_pass1(uint32_t* nmax) {
  __shared__ uint32_t ssub[CAP][4];
  __shared__ float ttab[TAB_N];
  __shared__ uint16_t qf[2][QCAP];
  __shared__ uint32_t qn[2];
  __shared__ uint32_t shN;
  __shared__ uint16_t aq_li[AQ_CAP];
  __shared__ float aq_u[AQ_CAP];
  __shared__ float aq_v[AQ_CAP];
  __shared__ uint32_t aqn;
  if (threadIdx.x == 0) { qn[0] = 0; qn[1] = 0; shN = 1; }
  build_shared(CAP, ssub, ttab);
  PC c = make_pc();
  uint32_t blockBase = blockIdx.x * N_TPB;
  // Phase A: level 0, accept1 fast path; everything else deferred to dense flush.
  for (int jc = 0; jc < ELEMS_PER_THREAD; jc += CHUNK_J) {
    if (threadIdx.x == 0) aqn = 0;
    __syncthreads();
    for (int j = jc; j < jc + CHUNK_J; ++j) {
      uint32_t e = blockBase + threadIdx.x + (uint32_t)j * TOTAL_THREADS;
      uint16_t li = (uint16_t)(((uint32_t)j << 8) | threadIdx.x);
      uint32_t ub = pbits(ssub[0][0], ssub[0][1], e);
      uint32_t vb = pbits(ssub[0][2], ssub[0][3], e);
      float u01 = bits_to_u01(ub);
      float v   = bits_to_u01(vb);
      float u = u01 - 0.5f;
      float us = 0.5f - fabsf(u);
      bool accept1 = (us >= (float)0.07) & (v <= c.v_r);
      bool pend = !accept1;
      uint32_t ai = wq_push(&aqn, pend);
      if (pend) {
        if (__builtin_expect(ai < AQ_CAP, 1)) {
          aq_li[ai] = li; aq_u[ai] = u; aq_v[ai] = v;
        } else {
          // overflow fallback: resolve level 0 inline, queue on failure
          float inner = c.twoa / us + c.bb;
          float k = floorf(__builtin_fmaf(inner, u, 500.43f));
          bool reject = (k < 0.0f) | ((us < (float)0.013) & (v > us));
          bool acc = false;
          if (!reject) {
            float s = xla_logf((v * c.inv_alpha) / (c.aa / (us * us) + c.bb));
            acc = (s <= t_lookup(k, ttab));
          }
          if (!acc) {
            uint32_t qi = atomicAdd(&qn[0], 1u);
            if (qi < QCAP) qf[0][qi] = li;
            else {
              float kk; uint32_t Lc = CAP;
              for (uint32_t t2 = 1; t2 < CAP; ++t2)
                if (trial(e, t2, ssub, c, ttab, kk)) { Lc = t2 + 1u; break; }
              atomicMax(&shN, Lc);
            }
          }
        }
      }
    }
    __syncthreads();
    uint32_t an = aqn; if (an > AQ_CAP) an = AQ_CAP;
    for (uint32_t i = threadIdx.x; i < an; i += N_TPB) {
      uint16_t li = aq_li[i];
      float u = aq_u[i], v = aq_v[i];
      float us = 0.5f - fabsf(u);
      float inner = c.twoa / us + c.bb;
      float k = floorf(__builtin_fmaf(inner, u, 500.43f));
      bool reject = (k < 0.0f) | ((us < (float)0.013) & (v > us));
      bool acc = false;
      if (!reject) {
        float s = xla_logf((v * c.inv_alpha) / (c.aa / (us * us) + c.bb));
        acc = (s <= t_lookup(k, ttab));
      }
      bool fail = !acc;
      uint32_t qi = wq_push(&qn[0], fail);
      if (fail) {
        if (__builtin_expect(qi < QCAP, 1)) qf[0][qi] = li;
        else {
          uint32_t e = blockBase + (li & 255u) + (uint32_t)(li >> 8) * TOTAL_THREADS;
          float kk; uint32_t Lc = CAP;
          for (uint32_t t2 = 1; t2 < CAP; ++t2)
            if (trial(e, t2, ssub, c, ttab, kk)) { Lc = t2 + 1u; break; }
          atomicMax(&shN, Lc);
        }
      }
    }
    __syncthreads();
  }
  // Level-synchronous queue phases.
  int cur = 0;
  uint32_t localN = 1;
  for (uint32_t t = 1; t < CAP; ++t) {
    uint32_t n = qn[cur]; if (n > QCAP) n = QCAP;
    if (n == 0) break;
    localN = t + 1u;
    if (threadIdx.x == 0) qn[cur ^ 1] = 0;
    __syncthreads();
    for (uint32_t i = threadIdx.x; i < n; i += N_TPB) {
      uint16_t li = qf[cur][i];
      uint32_t e = blockBase + (li & 255u) + (uint32_t)(li >> 8) * TOTAL_THREADS;
      float kk;
      bool fail = !trial(e, t, ssub, c, ttab, kk);
      uint32_t qi = wq_push(&qn[cur ^ 1], fail);
      if (fail) {
        if (__builtin_expect(qi < QCAP, 1)) qf[cur ^ 1][qi] = li;
        else {
          uint32_t Lc = CAP;
          for (uint32_t t2 = t + 1; t2 < CAP; ++t2)
            if (trial(e, t2, ssub, c, ttab, kk)) { Lc = t2 + 1u; break; }
          atomicMax(&shN, Lc);
        }
      }
    }
    __syncthreads();
    cur ^= 1;
  }
  __syncthreads();
  if (threadIdx.x == 0) {
    uint32_t m = shN; if (localN > m) m = localN;
    atomicMax(nmax, m);
  }
}

// ---------------- Pass 2: last-accept scanning N-1 .. 0 ----------------
__global__ __launch_bounds__(N_TPB) void pn_pass2(const float* __restrict__ img,
                                                  float* __restrict__ out,
                                                  const uint32_t* __restrict__ nptr) {
  __shared__ uint32_t ssub[CAP][4];
  __shared__ float ttab[TAB_N];
  __shared__ uint16_t qf[2][QCAP];
  __shared__ uint32_t qn[2];
  __shared__ uint16_t aq_li[AQ_CAP];
  __shared__ float aq_k[AQ_CAP];
  __shared__ float aq_us[AQ_CAP];
  __shared__ float aq_v[AQ_CAP];
  __shared__ uint32_t aqn;
  uint32_t N = *nptr;
  if (N < 1u) N = 1u;
  if (N > CAP) N = CAP;
  if (threadIdx.x == 0) { qn[0] = 0; qn[1] = 0; }
  build_shared(N, ssub, ttab);
  PC c = make_pc();
  uint32_t blockBase = blockIdx.x * N_TPB;
  uint32_t top = N - 1u;
  // Phase A: level N-1; accept1 -> write; reject -> queue; accept2 -> deferred dense.
  for (int jc = 0; jc < ELEMS_PER_THREAD; jc += CHUNK_J) {
    if (threadIdx.x == 0) aqn = 0;
    __syncthreads();
    for (int j = jc; j < jc + CHUNK_J; ++j) {
      uint32_t e = blockBase + threadIdx.x + (uint32_t)j * TOTAL_THREADS;
      uint16_t li = (uint16_t)(((uint32_t)j << 8) | threadIdx.x);
      uint32_t ub = pbits(ssub[top][0], ssub[top][1], e);
      uint32_t vb = pbits(ssub[top][2], ssub[top][3], e);
      float u01 = bits_to_u01(ub);
      float v   = bits_to_u01(vb);
      float u = u01 - 0.5f;
      float us = 0.5f - fabsf(u);
      float inner = c.twoa / us + c.bb;
      float k = floorf(__builtin_fmaf(inner, u, 500.43f));
      bool accept1 = (us >= (float)0.07) & (v <= c.v_r);
      bool reject  = (!accept1) & ((k < 0.0f) | ((us < (float)0.013) & (v > us)));
      bool need2   = (!accept1) & (!reject);
      if (accept1) out[e] = img[e] + k;
      uint32_t qi = wq_push(&qn[0], reject);
      if (reject) {
        if (__builtin_expect(qi < QCAP, 1)) qf[0][qi] = li;
        else {
          float kk, kf = -1.0f;
          for (int t2 = (int)top - 1; t2 >= 0; --t2)
            if (trial(e, (uint32_t)t2, ssub, c, ttab, kk)) { kf = kk; break; }
          out[e] = img[e] + kf;
        }
      }
      uint32_t ai = wq_push(&aqn, need2);
      if (need2) {
        if (__builtin_expect(ai < AQ_CAP, 1)) {
          aq_li[ai] = li; aq_k[ai] = k; aq_us[ai] = us; aq_v[ai] = v;
        } else {
          float s = xla_logf((v * c.inv_alpha) / (c.aa / (us * us) + c.bb));
          if (s <= t_lookup(k, ttab)) out[e] = img[e] + k;
          else {
            uint32_t qi2 = atomicAdd(&qn[0], 1u);
            if (qi2 < QCAP) qf[0][qi2] = li;
            else {
              float kk, kf = -1.0f;
              for (int t2 = (int)top - 1; t2 >= 0; --t2)
                if (trial(e, (uint32_t)t2, ssub, c, ttab, kk)) { kf = kk; break; }
              out[e] = img[e] + kf;
            }
          }
        }
      }
    }
    __syncthreads();
    uint32_t an = aqn; if (an > AQ_CAP) an = AQ_CAP;
    for (uint32_t i = threadIdx.x; i < an; i += N_TPB) {
      uint16_t li = aq_li[i];
      float k = aq_k[i], us = aq_us[i], v = aq_v[i];
      uint32_t e = blockBase + (li & 255u) + (uint32_t)(li >> 8) * TOTAL_THREADS;
      float s = xla_logf((v * c.inv_alpha) / (c.aa / (us * us) + c.bb));
      bool acc = (s <= t_lookup(k, ttab));
      if (acc) out[e] = img[e] + k;
      uint32_t qi = wq_push(&qn[0], !acc);
      if (!acc) {
        if (__builtin_expect(qi < QCAP, 1)) qf[0][qi] = li;
        else {
          float kk, kf = -1.0f;
          for (int t2 = (int)top - 1; t2 >= 0; --t2)
            if (trial(e, (uint32_t)t2, ssub, c, ttab, kk)) { kf = kk; break; }
          out[e] = img[e] + kf;
        }
      }
    }
    __syncthreads();
  }
  // Level-synchronous queue phases: levels top-1 .. 0.
  int cur = 0;
  for (int t = (int)top - 1; t >= 0; --t) {
    uint32_t n = qn[cur]; if (n > QCAP) n = QCAP;
    if (n == 0) break;
    if (threadIdx.x == 0) qn[cur ^ 1] = 0;
    __syncthreads();
    for (uint32_t i = threadIdx.x; i < n; i += N_TPB) {
      uint16_t li = qf[cur][i];
      uint32_t e = blockBase + (li & 255u) + (uint32_t)(li >> 8) * TOTAL_THREADS;
      float kk;
      bool acc = trial(e, (uint32_t)t, ssub, c, ttab, kk);
      if (acc) out[e] = img[e] + kk;
      uint32_t qi = wq_push(&qn[cur ^ 1], !acc);
      if (!acc) {
        if (__builtin_expect(qi < QCAP, 1)) qf[cur ^ 1][qi] = li;
        else {
          float kk2, kf = -1.0f;
          for (int t2 = t - 1; t2 >= 0; --t2)
            if (trial(e, (uint32_t)t2, ssub, c, ttab, kk2)) { kf = kk2; break; }
          out[e] = img[e] + kf;
        }
      }
    }
    __syncthreads();
    cur ^= 1;
  }
  // Drain: rejected at all levels -> k = -1 (JAX k_init).
  uint32_t n = qn[cur]; if (n > QCAP) n = QCAP;
  for (uint32_t i = threadIdx.x; i < n; i += N_TPB) {
    uint16_t li = qf[cur][i];
    uint32_t e = blockBase + (li & 255u) + (uint32_t)(li >> 8) * TOTAL_THREADS;
    out[e] = img[e] - 1.0f;
  }
}

extern "C" void kernel_launch(void* const* d_in, const int* in_sizes, int n_in,
                              void* d_out, int out_size, void* d_ws, size_t ws_size,
                              hipStream_t stream) {
  (void)in_sizes; (void)n_in; (void)out_size; (void)ws_size;
  const float* img = (const float*)d_in[0];
  float* out = (float*)d_out;
  uint32_t* nmax = (uint32_t*)d_ws;
  pn_init<<<1, 1, 0, stream>>>(nmax);
  pn_pass1<<<N_BLOCKS, N_TPB, 0, stream>>>(nmax);
  pn_pass2<<<N_BLOCKS, N_TPB, 0, stream>>>(img, out, nmax);
}